// Round 1
// baseline (8596.436 us; speedup 1.0000x reference)
//
#include <hip/hip_runtime.h>

#define N_WORDS 262144
#define N_TAGS  512
#define BDIM    768
#define MDIM    128

#define BM      64      // words per block (kernel 2)
#define NTHR    512     // threads per block (kernel 2)
#define CB      64      // BDIM chunk staged in LDS
#define WM_STRIDE 132   // padded stride for words_m tile (132%32=4 -> conflict-free)

// ---------------------------------------------------------------------------
// Kernel 1: tags_mT[m][t] = tags_embed[t] . tags_W[m] + tags_b[m]   (k-major)
//           t_sq[t] = sum_m tags_m[t][m]^2
// grid = N_TAGS blocks, 128 threads (thread = m)
// ---------------------------------------------------------------------------
__global__ __launch_bounds__(128) void tags_kernel(
    const float* __restrict__ tags_embed,   // [T][B]
    const float* __restrict__ tags_W,       // [M][B]
    const float* __restrict__ tags_b,       // [M]
    float* __restrict__ tags_mT,            // [M][T]
    float* __restrict__ t_sq)               // [T]
{
    __shared__ __align__(16) float sE[BDIM];
    __shared__ float red[128];
    const int t = blockIdx.x;
    const int m = threadIdx.x;

    for (int i = m; i < BDIM; i += 128) sE[i] = tags_embed[(size_t)t * BDIM + i];
    __syncthreads();

    float acc = tags_b[m];
    const float* Wr = tags_W + (size_t)m * BDIM;
    #pragma unroll 8
    for (int b = 0; b < BDIM; b += 4) {
        float4 w4 = *reinterpret_cast<const float4*>(Wr + b);
        float4 e4 = *reinterpret_cast<const float4*>(&sE[b]);
        acc += w4.x * e4.x + w4.y * e4.y + w4.z * e4.z + w4.w * e4.w;
    }
    tags_mT[(size_t)m * N_TAGS + t] = acc;

    red[m] = acc * acc;
    __syncthreads();
    for (int s = 64; s > 0; s >>= 1) {
        if (m < s) red[m] += red[m + s];
        __syncthreads();
    }
    if (m == 0) t_sq[t] = red[0];
}

// ---------------------------------------------------------------------------
// Kernel 2: fused words projection + distances + softmax/log_softmax
// grid = N_WORDS/BM blocks, NTHR threads
// Phase A: words_m tile [BM][MDIM] in LDS (fp32, chunked LDS staging of embed)
// Phase B: li[w][t] = 2*(words_m[w] . tags_m[t]) - t_sq[t]  (w_sq cancels in
//          softmax/log_softmax), then in-register softmax per word row.
// ---------------------------------------------------------------------------
__global__ __launch_bounds__(NTHR) void words_kernel(
    const float* __restrict__ words_embed,  // [N][B]
    const float* __restrict__ words_W,      // [M][B]
    const float* __restrict__ words_b,      // [M]
    const float* __restrict__ tags_mT,      // [M][T]
    const float* __restrict__ t_sq,         // [T]
    float* __restrict__ out_logp,           // [N][T]
    float* __restrict__ out_p)              // [N][T]
{
    __shared__ __align__(16) float sEmb[BM * CB];        // 16 KB
    __shared__ __align__(16) float sWm[BM * WM_STRIDE];  // 33 KB

    const int tid = threadIdx.x;
    const int w0  = blockIdx.x * BM;

    // ---------------- Phase A ----------------
    const int m  = tid & 127;   // output metric dim
    const int wq = tid >> 7;    // word quarter: wq*16 .. wq*16+15 (wave-uniform)

    float acc[16];
    {
        const float wb = words_b[m];
        #pragma unroll
        for (int i = 0; i < 16; ++i) acc[i] = wb;
    }

    for (int kc = 0; kc < BDIM; kc += CB) {
        // stage sEmb[BM][CB]: BM*CB/4 = 1024 float4, 2 per thread, coalesced
        #pragma unroll
        for (int r = 0; r < 2; ++r) {
            int f = tid + NTHR * r;        // float4 index
            int w = f >> 4;                // CB/4 = 16 float4 per row
            int c = f & 15;
            *reinterpret_cast<float4*>(&sEmb[w * CB + c * 4]) =
                *reinterpret_cast<const float4*>(
                    &words_embed[(size_t)(w0 + w) * BDIM + kc + c * 4]);
        }
        __syncthreads();

        const float* Wp = words_W + (size_t)m * BDIM + kc;
        #pragma unroll 4
        for (int bb = 0; bb < CB; bb += 4) {
            float4 w4 = *reinterpret_cast<const float4*>(Wp + bb);
            #pragma unroll
            for (int wi = 0; wi < 16; ++wi) {
                float4 e4 = *reinterpret_cast<const float4*>(
                    &sEmb[(wq * 16 + wi) * CB + bb]);  // wave-uniform addr (broadcast)
                acc[wi] += w4.x * e4.x + w4.y * e4.y + w4.z * e4.z + w4.w * e4.w;
            }
        }
        __syncthreads();
    }
    #pragma unroll
    for (int wi = 0; wi < 16; ++wi)
        sWm[(wq * 16 + wi) * WM_STRIDE + m] = acc[wi];
    __syncthreads();

    // ---------------- Phase B ----------------
    const int w = tid >> 3;    // word within tile, 0..63
    const int g = tid & 7;     // tag group: tags g*64 .. g*64+63

    float acc2[64];
    #pragma unroll
    for (int j = 0; j < 64; ++j) acc2[j] = 0.f;

    const float* tT = tags_mT + g * 64;
    #pragma unroll 2
    for (int k = 0; k < MDIM; ++k) {
        float wm = sWm[w * WM_STRIDE + k];   // 8 distinct banks across lanes
        const float4* row = reinterpret_cast<const float4*>(tT + (size_t)k * N_TAGS);
        #pragma unroll
        for (int j4 = 0; j4 < 16; ++j4) {
            float4 tg = row[j4];
            acc2[4 * j4 + 0] += wm * tg.x;
            acc2[4 * j4 + 1] += wm * tg.y;
            acc2[4 * j4 + 2] += wm * tg.z;
            acc2[4 * j4 + 3] += wm * tg.w;
        }
    }

    // li = 2*dot - t_sq  (in place)
    {
        const float4* q4 = reinterpret_cast<const float4*>(t_sq + g * 64);
        #pragma unroll
        for (int j4 = 0; j4 < 16; ++j4) {
            float4 q = q4[j4];
            acc2[4 * j4 + 0] = 2.f * acc2[4 * j4 + 0] - q.x;
            acc2[4 * j4 + 1] = 2.f * acc2[4 * j4 + 1] - q.y;
            acc2[4 * j4 + 2] = 2.f * acc2[4 * j4 + 2] - q.z;
            acc2[4 * j4 + 3] = 2.f * acc2[4 * j4 + 3] - q.w;
        }
    }

    // row max over 64 local + 8 lanes (lanes sharing w are consecutive)
    float mx = acc2[0];
    #pragma unroll
    for (int j = 1; j < 64; ++j) mx = fmaxf(mx, acc2[j]);
    #pragma unroll
    for (int d = 1; d < 8; d <<= 1) mx = fmaxf(mx, __shfl_xor(mx, d, 64));

    float s = 0.f;
    #pragma unroll
    for (int j = 0; j < 64; ++j) s += __expf(acc2[j] - mx);
    #pragma unroll
    for (int d = 1; d < 8; d <<= 1) s += __shfl_xor(s, d, 64);

    const float logs = __logf(s);
    const float invs = 1.f / s;
    const float neg  = mx + logs;

    const size_t rowoff = (size_t)(w0 + w) * N_TAGS + g * 64;
    #pragma unroll
    for (int j4 = 0; j4 < 16; ++j4) {
        float4 lp, pp;
        lp.x = acc2[4 * j4 + 0] - neg;  pp.x = __expf(acc2[4 * j4 + 0] - mx) * invs;
        lp.y = acc2[4 * j4 + 1] - neg;  pp.y = __expf(acc2[4 * j4 + 1] - mx) * invs;
        lp.z = acc2[4 * j4 + 2] - neg;  pp.z = __expf(acc2[4 * j4 + 2] - mx) * invs;
        lp.w = acc2[4 * j4 + 3] - neg;  pp.w = __expf(acc2[4 * j4 + 3] - mx) * invs;
        *reinterpret_cast<float4*>(&out_logp[rowoff + 4 * j4]) = lp;
        *reinterpret_cast<float4*>(&out_p[rowoff + 4 * j4])    = pp;
    }
}

extern "C" void kernel_launch(void* const* d_in, const int* in_sizes, int n_in,
                              void* d_out, int out_size, void* d_ws, size_t ws_size,
                              hipStream_t stream) {
    const float* tags_embed  = (const float*)d_in[0];
    const float* words_embed = (const float*)d_in[1];
    const float* tags_W      = (const float*)d_in[2];
    const float* tags_b      = (const float*)d_in[3];
    const float* words_W     = (const float*)d_in[4];
    const float* words_b     = (const float*)d_in[5];

    float* out_logp = (float*)d_out;
    float* out_p    = out_logp + (size_t)N_WORDS * N_TAGS;

    // ws layout: tags_mT [MDIM][N_TAGS] fp32, then t_sq [N_TAGS]
    float* tags_mT = (float*)d_ws;
    float* tsq     = tags_mT + (size_t)MDIM * N_TAGS;

    tags_kernel<<<N_TAGS, 128, 0, stream>>>(tags_embed, tags_W, tags_b, tags_mT, tsq);
    words_kernel<<<N_WORDS / BM, NTHR, 0, stream>>>(
        words_embed, words_W, words_b, tags_mT, tsq, out_logp, out_p);
}

// Round 2
// 1042.464 us; speedup vs baseline: 8.2463x; 8.2463x over previous
//
#include <hip/hip_runtime.h>

#define N_WORDS 262144
#define N_TAGS  512
#define BDIM    768
#define MDIM    128

typedef __attribute__((ext_vector_type(8))) short  bf16x8;
typedef __attribute__((ext_vector_type(4))) float  f32x4;
typedef __attribute__((ext_vector_type(4))) int    i32x4;

union FragU { i32x4 i; bf16x8 h; };

// RNE fp32 -> bf16 (inputs finite)
__device__ inline unsigned bf16_1(float a) {
    union { float f; unsigned u; } ua; ua.f = a;
    unsigned x = ua.u;
    x += 0x7fffu + ((x >> 16) & 1u);
    return x >> 16;
}
// pack two fp32 -> (bf16(b)<<16)|bf16(a)
__device__ inline unsigned bf16_2(float a, float b) {
    union { float f; unsigned u; } ua, ub; ua.f = a; ub.f = b;
    unsigned x = ua.u, y = ub.u;
    x += 0x7fffu + ((x >> 16) & 1u);
    y += 0x7fffu + ((y >> 16) & 1u);
    return (x >> 16) | (y & 0xffff0000u);
}

// ---------------------------------------------------------------------------
// tags: tags_m = tags_embed @ tags_W.T + tags_b  (fp32)
//   Tbf[t][m] = bf16(2 * tags_m[t][m])   (k-contiguous A-fragment layout)
//   tsq[t]    = sum_m tags_m^2           (fp32)
// ---------------------------------------------------------------------------
__global__ __launch_bounds__(128) void tags_kernel(
    const float* __restrict__ tags_embed, const float* __restrict__ tags_W,
    const float* __restrict__ tags_b, unsigned short* __restrict__ Tbf,
    float* __restrict__ tsq)
{
    __shared__ __align__(16) float sE[BDIM];
    __shared__ float red[128];
    const int t = blockIdx.x;
    const int m = threadIdx.x;

    for (int i = m; i < BDIM; i += 128) sE[i] = tags_embed[(size_t)t * BDIM + i];
    __syncthreads();

    float acc = tags_b[m];
    const float* Wr = tags_W + (size_t)m * BDIM;
    #pragma unroll 8
    for (int b = 0; b < BDIM; b += 4) {
        float4 w4 = *reinterpret_cast<const float4*>(Wr + b);
        float4 e4 = *reinterpret_cast<const float4*>(&sE[b]);
        acc += w4.x * e4.x + w4.y * e4.y + w4.z * e4.z + w4.w * e4.w;
    }
    Tbf[(size_t)t * MDIM + m] = (unsigned short)bf16_1(2.0f * acc);

    red[m] = acc * acc;
    __syncthreads();
    for (int s = 64; s > 0; s >>= 1) {
        if (m < s) red[m] += red[m + s];
        __syncthreads();
    }
    if (m == 0) tsq[t] = red[0];
}

// words_W fp32 [128][768] -> bf16 (RNE), packed pairs
__global__ __launch_bounds__(256) void wconv_kernel(
    const float* __restrict__ W, unsigned* __restrict__ Wbf)
{
    int i = blockIdx.x * 256 + threadIdx.x;          // 49152 u32 pairs
    float2 f = reinterpret_cast<const float2*>(W)[i];
    Wbf[i] = bf16_2(f.x, f.y);
}

// ---------------------------------------------------------------------------
// Main: per wave, 16 words. GEMM1 (transposed) -> shuffle transpose ->
// GEMM2 -> softmax -> stores. No LDS, no barriers.
// ---------------------------------------------------------------------------
__global__ __launch_bounds__(256, 2) void words_kernel(
    const float* __restrict__ embed,                 // [N][768] fp32
    const unsigned short* __restrict__ Wbf,          // [128][768] bf16
    const float* __restrict__ bias,                  // [128] fp32
    const unsigned short* __restrict__ Tbf,          // [512][128] bf16 (2*tags_m)
    const float* __restrict__ tsq,                   // [512] fp32
    float* __restrict__ out_logp, float* __restrict__ out_p)
{
    const int lane = threadIdx.x & 63;
    const int wv   = threadIdx.x >> 6;
    const int w    = lane & 15;          // word within wave's 16
    const int q    = lane >> 4;          // k-group 0..3
    const int word0 = blockIdx.x * 64 + wv * 16;

    // ---------------- GEMM1: C1T[m=128][word=16] = W . E^T ----------------
    f32x4 acc1[8];
    #pragma unroll
    for (int mt = 0; mt < 8; ++mt) acc1[mt] = (f32x4){0.f, 0.f, 0.f, 0.f};

    const float* erow = embed + (size_t)(word0 + w) * BDIM + q * 8;
    #pragma unroll
    for (int ks = 0; ks < 24; ++ks) {
        // B1 fragment: embed row (word w), k = ks*32 + q*8 .. +7, fp32->bf16
        f32x4 e0 = *reinterpret_cast<const f32x4*>(erow + ks * 32);
        f32x4 e1 = *reinterpret_cast<const f32x4*>(erow + ks * 32 + 4);
        FragU bu;
        bu.i = (i32x4){ (int)bf16_2(e0.x, e0.y), (int)bf16_2(e0.z, e0.w),
                        (int)bf16_2(e1.x, e1.y), (int)bf16_2(e1.z, e1.w) };
        #pragma unroll
        for (int mt = 0; mt < 8; ++mt) {
            bf16x8 af = *reinterpret_cast<const bf16x8*>(
                Wbf + (size_t)(mt * 16 + w) * BDIM + ks * 32 + q * 8);
            acc1[mt] = __builtin_amdgcn_mfma_f32_16x16x32_bf16(af, bu.h, acc1[mt], 0, 0, 0);
        }
    }

    // bias + pack to bf16 pairs: lane (w,q) holds m = mt*16 + q*4 + r
    unsigned pk[8][2];
    #pragma unroll
    for (int mt = 0; mt < 8; ++mt) {
        f32x4 b4 = *reinterpret_cast<const f32x4*>(bias + mt * 16 + q * 4);
        f32x4 v  = acc1[mt] + b4;
        pk[mt][0] = bf16_2(v.x, v.y);
        pk[mt][1] = bf16_2(v.z, v.w);
    }

    // shuffle transpose: B2 fragment e = Wm[w][ks*32 + q*8 + e]
    // value m lives at lane (w, (m>>2)&3), tile m>>4, reg m&3
    const int src0 = w + 16 * ((2 * q) & 3);
    const int src1 = w + 16 * ((2 * q + 1) & 3);
    const int hi   = q >> 1;
    unsigned px[4][4];
    #pragma unroll
    for (int ks = 0; ks < 4; ++ks) {
        unsigned a0 = __shfl(pk[2 * ks][0],     src0, 64);
        unsigned a1 = __shfl(pk[2 * ks][1],     src0, 64);
        unsigned a2 = __shfl(pk[2 * ks][0],     src1, 64);
        unsigned a3 = __shfl(pk[2 * ks][1],     src1, 64);
        unsigned b0 = __shfl(pk[2 * ks + 1][0], src0, 64);
        unsigned b1 = __shfl(pk[2 * ks + 1][1], src0, 64);
        unsigned b2 = __shfl(pk[2 * ks + 1][0], src1, 64);
        unsigned b3 = __shfl(pk[2 * ks + 1][1], src1, 64);
        px[ks][0] = hi ? b0 : a0;
        px[ks][1] = hi ? b1 : a1;
        px[ks][2] = hi ? b2 : a2;
        px[ks][3] = hi ? b3 : a3;
    }
    FragU bf2[4];
    #pragma unroll
    for (int ks = 0; ks < 4; ++ks)
        bf2[ks].i = (i32x4){ (int)px[ks][0], (int)px[ks][1],
                             (int)px[ks][2], (int)px[ks][3] };

    // ---------------- GEMM2: D2T[tag=512][word=16] = (2*Tm) . Wm^T --------
    f32x4 acc2[32];
    #pragma unroll
    for (int tt = 0; tt < 32; ++tt) acc2[tt] = (f32x4){0.f, 0.f, 0.f, 0.f};

    #pragma unroll
    for (int tt = 0; tt < 32; ++tt) {
        #pragma unroll
        for (int ks = 0; ks < 4; ++ks) {
            bf16x8 af = *reinterpret_cast<const bf16x8*>(
                Tbf + (size_t)(tt * 16 + w) * MDIM + ks * 32 + q * 8);
            acc2[tt] = __builtin_amdgcn_mfma_f32_16x16x32_bf16(af, bf2[ks].h, acc2[tt], 0, 0, 0);
        }
    }

    // x = 2*w.t - t^2  (w^2 cancels in softmax). tag = tt*16 + q*4 + r
    float mx = -3.0e38f;
    #pragma unroll
    for (int tt = 0; tt < 32; ++tt) {
        f32x4 s4 = *reinterpret_cast<const f32x4*>(tsq + tt * 16 + q * 4);
        acc2[tt] -= s4;
        mx = fmaxf(mx, fmaxf(fmaxf(acc2[tt].x, acc2[tt].y),
                             fmaxf(acc2[tt].z, acc2[tt].w)));
    }
    mx = fmaxf(mx, __shfl_xor(mx, 16, 64));
    mx = fmaxf(mx, __shfl_xor(mx, 32, 64));

    float s = 0.f;
    #pragma unroll
    for (int tt = 0; tt < 32; ++tt) {
        s += __expf(acc2[tt].x - mx);
        s += __expf(acc2[tt].y - mx);
        s += __expf(acc2[tt].z - mx);
        s += __expf(acc2[tt].w - mx);
    }
    s += __shfl_xor(s, 16, 64);
    s += __shfl_xor(s, 32, 64);

    const float neg = mx + __logf(s);

    const size_t row = (size_t)(word0 + w) * N_TAGS;
    #pragma unroll
    for (int tt = 0; tt < 32; ++tt) {
        f32x4 lp, pp;
        lp.x = acc2[tt].x - neg;  pp.x = __expf(lp.x);
        lp.y = acc2[tt].y - neg;  pp.y = __expf(lp.y);
        lp.z = acc2[tt].z - neg;  pp.z = __expf(lp.z);
        lp.w = acc2[tt].w - neg;  pp.w = __expf(lp.w);
        *reinterpret_cast<f32x4*>(out_logp + row + tt * 16 + q * 4) = lp;
        *reinterpret_cast<f32x4*>(out_p    + row + tt * 16 + q * 4) = pp;
    }
}

extern "C" void kernel_launch(void* const* d_in, const int* in_sizes, int n_in,
                              void* d_out, int out_size, void* d_ws, size_t ws_size,
                              hipStream_t stream) {
    const float* tags_embed  = (const float*)d_in[0];
    const float* words_embed = (const float*)d_in[1];
    const float* tags_W      = (const float*)d_in[2];
    const float* tags_b      = (const float*)d_in[3];
    const float* words_W     = (const float*)d_in[4];
    const float* words_b     = (const float*)d_in[5];

    float* out_logp = (float*)d_out;
    float* out_p    = out_logp + (size_t)N_WORDS * N_TAGS;

    // ws: Tbf [512][128] bf16 | tsq [512] f32 | Wbf [128][768] bf16
    unsigned short* Tbf = (unsigned short*)d_ws;
    float*          tsq = (float*)(Tbf + (size_t)N_TAGS * MDIM);
    unsigned short* Wbf = (unsigned short*)(tsq + N_TAGS);

    tags_kernel<<<N_TAGS, 128, 0, stream>>>(tags_embed, tags_W, tags_b, Tbf, tsq);
    wconv_kernel<<<(MDIM * BDIM / 2) / 256, 256, 0, stream>>>(words_W, (unsigned*)Wbf);
    words_kernel<<<N_WORDS / 64, 256, 0, stream>>>(
        words_embed, Wbf, words_b, Tbf, tsq, out_logp, out_p);
}